// Round 7
// baseline (257.597 us; speedup 1.0000x reference)
//
#include <hip/hip_runtime.h>

// Problem constants (match reference)
constexpr int   B_ = 8;
constexpr int   T_ = 100;
constexpr int   NPAIRS = B_ * T_;      // 800
constexpr int   N_ = 100000;
constexpr float MARGIN_ = 0.1f;
constexpr float THRESHOLD_ = 0.5f;
constexpr float BIG_ = 1000000000.0f;

// Main-kernel geometry
constexpr int PER   = 98;              // splats per block
constexpr int NBLK  = 1024;            // k_main blocks
constexpr int NREC  = NBLK * PER;      // 100352 padded splat records
constexpr int NSLOT = 1024;            // padded pair slots (8 batches x 128)

// Workspace layout (bytes)
constexpr size_t PACK_OFF   = 0;                                   // NREC x 64B records
constexpr size_t RES_OFF    = PACK_OFF + (size_t)NREC * 64;        // float[NBLK][NSLOT] = 4MB
constexpr size_t SLOT_OFF   = RES_OFF + (size_t)NBLK * NSLOT * 4;  // float4[NSLOT]
constexpr size_t BOUNDS_OFF = SLOT_OFF + (size_t)NSLOT * 16;       // float[48]: l[8][3], u[8][3]

// fast hardware sqrt: single v_sqrt_f32
__device__ __forceinline__ float fsqrt(float x) { return __builtin_amdgcn_sqrtf(x); }

// K1: retrajs -> padded slot-pairs, per-b AABB bounds, zero out. 1 block x 1024.
// Slot g (0..1023): batch = g>>7, r = g&127; r<100 -> pair batch*100+r, else dummy.
__global__ void k_prep(const float* __restrict__ outputs,
                       const float* __restrict__ c2ws,
                       const float* __restrict__ ss,
                       char* ws, float* __restrict__ out) {
    __shared__ float re_s[NPAIRS * 3];
    int tid = threadIdx.x;
    float* bounds = (float*)(ws + BOUNDS_OFF);

    if (tid == 0) out[0] = 0.f;  // k_red accumulates via atomicAdd

    if (tid < NPAIRS) {
        int b = tid / T_;
        float s = ss[b];
        const float* o = outputs + tid * 3;
        float o0 = o[0], o1 = o[1], o2 = o[2];
        const float* c = c2ws + b * 16;
#pragma unroll
        for (int e = 0; e < 3; e++) {
            re_s[tid * 3 + e] =
                (o0 * c[e * 4 + 0] + o1 * c[e * 4 + 1] + o2 * c[e * 4 + 2]) * s + c[e * 4 + 3];
        }
    }
    __syncthreads();

    if (tid < 24) {
        int b = tid / 3, e = tid - b * 3;
        float mx = -3.4e38f, mn = 3.4e38f;
        for (int t = 0; t < T_; t++) {
            float v = re_s[(b * T_ + t) * 3 + e];
            mx = fmaxf(mx, v);
            mn = fminf(mn, v);
        }
        float thres = THRESHOLD_ * ss[0];  // reference uses scene_scales[0] for all b
        bounds[b * 3 + e]      = mn - thres;  // lvals
        bounds[24 + b * 3 + e] = mx + thres;  // uvals
    }

    // padded slot-pairs
    int bb = tid >> 7, r = tid & 127;
    float4 q = make_float4(0.f, 0.f, 0.f, 0.f);
    if (r < T_) {
        int p = bb * T_ + r;
        q = make_float4(re_s[p * 3 + 0], re_s[p * 3 + 1], re_s[p * 3 + 2], 1.f);
    }
    ((float4*)(ws + SLOT_OFF))[tid] = q;
}

// K2: pack per-splat 64B record: [mx,my,mz,_][e0,e2,e4,e6][e1,e3,e5,e7][pad]
//     e_b = inside_b ? maxrad+MARGIN : -BIG. Padded records (n>=N) get e=-BIG.
__global__ __launch_bounds__(256) void k_pack(const float* __restrict__ means,
                                              const float* __restrict__ scales,
                                              char* ws) {
    int n = blockIdx.x * 256 + threadIdx.x;   // grid covers exactly NREC
    const float* bounds = (const float*)(ws + BOUNDS_OFF);
    float4* rec = (float4*)(ws + PACK_OFF + (size_t)n * 64);
    if (n < N_) {
        float mx = means[(size_t)n * 3 + 0];
        float my = means[(size_t)n * 3 + 1];
        float mz = means[(size_t)n * 3 + 2];
        float msr = fmaxf(fmaxf(scales[(size_t)n * 3 + 0], scales[(size_t)n * 3 + 1]),
                          scales[(size_t)n * 3 + 2]) + MARGIN_;
        float e[8];
#pragma unroll
        for (int b = 0; b < 8; b++) {
            bool in = (mx >= bounds[b * 3 + 0]) & (mx <= bounds[24 + b * 3 + 0]) &
                      (my >= bounds[b * 3 + 1]) & (my <= bounds[24 + b * 3 + 1]) &
                      (mz >= bounds[b * 3 + 2]) & (mz <= bounds[24 + b * 3 + 2]);
            e[b] = in ? msr : -BIG_;
        }
        rec[0] = make_float4(mx, my, mz, 0.f);
        rec[1] = make_float4(e[0], e[2], e[4], e[6]);
        rec[2] = make_float4(e[1], e[3], e[5], e[7]);
    } else {
        rec[0] = make_float4(0.f, 0.f, 0.f, 0.f);
        rec[1] = make_float4(-BIG_, -BIG_, -BIG_, -BIG_);
        rec[2] = make_float4(-BIG_, -BIG_, -BIG_, -BIG_);
    }
}

// K3: main loop. NO LDS, NO barriers. Each thread owns 4 slot-pairs (named
// scalars). Splat records are wave-uniform scalar loads (s_load path): 2 x
// dwordx4 per splat. Waves 0,1 read eff at +16 ({e0,e2,e4,e6}); waves 2,3 at
// +32 ({e1,e3,e5,e7}) -- matches slot->batch mapping batch=(4j+w)>>1.
// Results: plain coalesced stores to res[block][slot] (no contended atomics).
__global__ __launch_bounds__(256) void k_main(const char* __restrict__ wsc,
                                              char* __restrict__ ws) {
    int tid = threadIdx.x;
    const float4* sp = (const float4*)(wsc + SLOT_OFF);
    float4 q0 = sp[tid];
    float4 q1 = sp[tid + 256];
    float4 q2 = sp[tid + 512];
    float4 q3 = sp[tid + 768];

    int effoff = 16 + (((__builtin_amdgcn_readfirstlane(tid) >> 7) & 1) << 4);  // 16 | 32
    const char* rec = wsc + PACK_OFF + (size_t)blockIdx.x * PER * 64;

    float mn0 = BIG_, mn1 = BIG_, mn2 = BIG_, mn3 = BIG_;
#pragma unroll 2
    for (int i = 0; i < PER; i++) {
        float4 pos = *(const float4*)(rec);
        float4 ef  = *(const float4*)(rec + effoff);
        rec += 64;
        float dx, dy, dz, d2;
        dx = q0.x - pos.x; dy = q0.y - pos.y; dz = q0.z - pos.z;
        d2 = fmaf(dz, dz, fmaf(dy, dy, dx * dx));
        mn0 = fminf(mn0, fsqrt(d2) - ef.x);
        dx = q1.x - pos.x; dy = q1.y - pos.y; dz = q1.z - pos.z;
        d2 = fmaf(dz, dz, fmaf(dy, dy, dx * dx));
        mn1 = fminf(mn1, fsqrt(d2) - ef.y);
        dx = q2.x - pos.x; dy = q2.y - pos.y; dz = q2.z - pos.z;
        d2 = fmaf(dz, dz, fmaf(dy, dy, dx * dx));
        mn2 = fminf(mn2, fsqrt(d2) - ef.z);
        dx = q3.x - pos.x; dy = q3.y - pos.y; dz = q3.z - pos.z;
        d2 = fmaf(dz, dz, fmaf(dy, dy, dx * dx));
        mn3 = fminf(mn3, fsqrt(d2) - ef.w);
    }

    float* res = (float*)(ws + RES_OFF) + (size_t)blockIdx.x * NSLOT;
    res[tid]       = mn0;
    res[tid + 256] = mn1;
    res[tid + 512] = mn2;
    res[tid + 768] = mn3;
}

// K4: column-min over the NBLK block-results, relu, sum -> out. 4 blocks x 256.
__global__ __launch_bounds__(256) void k_red(const char* __restrict__ wsc,
                                             float* __restrict__ out) {
    int tid = threadIdx.x;
    int slot = blockIdx.x * 256 + tid;
    const float* res = (const float*)(wsc + RES_OFF);
    float mn = BIG_;
#pragma unroll 4
    for (int k = 0; k < NBLK; k++) mn = fminf(mn, res[(size_t)k * NSLOT + slot]);
    float acc = ((slot & 127) < T_) ? fmaxf(0.f, -mn) : 0.f;  // mask dummy slots
#pragma unroll
    for (int off = 32; off; off >>= 1) acc += __shfl_down(acc, off, 64);
    __shared__ float wsum[4];
    if ((tid & 63) == 0) wsum[tid >> 6] = acc;
    __syncthreads();
    if (tid == 0)
        atomicAdd(out, (wsum[0] + wsum[1] + wsum[2] + wsum[3]) * (1.0f / (float)NPAIRS));
}

extern "C" void kernel_launch(void* const* d_in, const int* in_sizes, int n_in,
                              void* d_out, int out_size, void* d_ws, size_t ws_size,
                              hipStream_t stream) {
    const float* outputs = (const float*)d_in[0];   // (B,T,3)
    const float* c2ws    = (const float*)d_in[1];   // (B,4,4)
    const float* ss      = (const float*)d_in[2];   // (B,)
    const float* means   = (const float*)d_in[3];   // (N,3)
    const float* scales  = (const float*)d_in[4];   // (N,3)
    float* out = (float*)d_out;
    char*  ws  = (char*)d_ws;

    hipLaunchKernelGGL(k_prep, dim3(1), dim3(1024), 0, stream, outputs, c2ws, ss, ws, out);
    hipLaunchKernelGGL(k_pack, dim3(NREC / 256), dim3(256), 0, stream, means, scales, ws);
    hipLaunchKernelGGL(k_main, dim3(NBLK), dim3(256), 0, stream, (const char*)ws, ws);
    hipLaunchKernelGGL(k_red, dim3(NSLOT / 256), dim3(256), 0, stream, (const char*)ws, out);
}

// Round 8
// 109.578 us; speedup vs baseline: 2.3508x; 2.3508x over previous
//
#include <hip/hip_runtime.h>

// Problem constants (match reference)
constexpr int   B_ = 8;
constexpr int   T_ = 100;
constexpr int   NPAIRS = B_ * T_;      // 800
constexpr int   N_ = 100000;
constexpr float MARGIN_ = 0.1f;
constexpr float THRESHOLD_ = 0.5f;
constexpr float BIG_ = 1000000000.0f;

// Main-kernel geometry
constexpr int PER   = 98;              // splats per block
constexpr int NBLK  = 1024;            // k_main blocks
constexpr int NREC  = NBLK * PER;      // 100352 padded splat records
constexpr int NSLOT = 1024;            // padded pair slots (8 batches x 128)
constexpr int KCH   = 16;              // res-rows per reduction block
constexpr int NRED  = NBLK / KCH;      // 64 reduction blocks

// Workspace layout (bytes)
constexpr size_t PACK_OFF   = 0;                                   // NREC x 64B records
constexpr size_t RES_OFF    = PACK_OFF + (size_t)NREC * 64;        // float[NBLK][NSLOT] = 4MB
constexpr size_t SLOT_OFF   = RES_OFF + (size_t)NBLK * NSLOT * 4;  // float4[NSLOT]
constexpr size_t BOUNDS_OFF = SLOT_OFF + (size_t)NSLOT * 16;       // float[48]: l[8][3], u[8][3]
constexpr size_t KEYS_OFF   = BOUNDS_OFF + 256;                    // uint[NSLOT] min-keys
constexpr size_t CNT_OFF    = KEYS_OFF + (size_t)NSLOT * 4;        // uint: finished-block counter

// fast hardware sqrt: single v_sqrt_f32
__device__ __forceinline__ float fsqrt(float x) { return __builtin_amdgcn_sqrtf(x); }

// Map float -> uint such that uint order == float order (handles negatives).
__device__ __forceinline__ unsigned fkey(float f) {
    unsigned u = __float_as_uint(f);
    return (u & 0x80000000u) ? ~u : (u | 0x80000000u);
}

// K1: retrajs -> padded slot-pairs, per-b AABB bounds, init keys+cnt. 1 block x 1024.
// Slot g (0..1023): batch = g>>7, r = g&127; r<100 -> pair batch*100+r, else dummy.
__global__ void k_prep(const float* __restrict__ outputs,
                       const float* __restrict__ c2ws,
                       const float* __restrict__ ss,
                       char* ws) {
    __shared__ float re_s[NPAIRS * 3];
    int tid = threadIdx.x;
    float* bounds = (float*)(ws + BOUNDS_OFF);

    ((unsigned*)(ws + KEYS_OFF))[tid] = fkey(BIG_);   // re-init every call (ws re-poisoned)
    if (tid == 0) *(unsigned*)(ws + CNT_OFF) = 0;

    if (tid < NPAIRS) {
        int b = tid / T_;
        float s = ss[b];
        const float* o = outputs + tid * 3;
        float o0 = o[0], o1 = o[1], o2 = o[2];
        const float* c = c2ws + b * 16;
#pragma unroll
        for (int e = 0; e < 3; e++) {
            re_s[tid * 3 + e] =
                (o0 * c[e * 4 + 0] + o1 * c[e * 4 + 1] + o2 * c[e * 4 + 2]) * s + c[e * 4 + 3];
        }
    }
    __syncthreads();

    if (tid < 24) {
        int b = tid / 3, e = tid - b * 3;
        float mx = -3.4e38f, mn = 3.4e38f;
        for (int t = 0; t < T_; t++) {
            float v = re_s[(b * T_ + t) * 3 + e];
            mx = fmaxf(mx, v);
            mn = fminf(mn, v);
        }
        float thres = THRESHOLD_ * ss[0];  // reference uses scene_scales[0] for all b
        bounds[b * 3 + e]      = mn - thres;  // lvals
        bounds[24 + b * 3 + e] = mx + thres;  // uvals
    }

    // padded slot-pairs
    int bb = tid >> 7, r = tid & 127;
    float4 q = make_float4(0.f, 0.f, 0.f, 0.f);
    if (r < T_) {
        int p = bb * T_ + r;
        q = make_float4(re_s[p * 3 + 0], re_s[p * 3 + 1], re_s[p * 3 + 2], 1.f);
    }
    ((float4*)(ws + SLOT_OFF))[tid] = q;
}

// K2: pack per-splat 64B record: [mx,my,mz,_][e0,e2,e4,e6][e1,e3,e5,e7][pad]
//     e_b = inside_b ? maxrad+MARGIN : -BIG. Padded records (n>=N) get e=-BIG.
__global__ __launch_bounds__(256) void k_pack(const float* __restrict__ means,
                                              const float* __restrict__ scales,
                                              char* ws) {
    int n = blockIdx.x * 256 + threadIdx.x;   // grid covers exactly NREC
    const float* bounds = (const float*)(ws + BOUNDS_OFF);
    float4* rec = (float4*)(ws + PACK_OFF + (size_t)n * 64);
    if (n < N_) {
        float mx = means[(size_t)n * 3 + 0];
        float my = means[(size_t)n * 3 + 1];
        float mz = means[(size_t)n * 3 + 2];
        float msr = fmaxf(fmaxf(scales[(size_t)n * 3 + 0], scales[(size_t)n * 3 + 1]),
                          scales[(size_t)n * 3 + 2]) + MARGIN_;
        float e[8];
#pragma unroll
        for (int b = 0; b < 8; b++) {
            bool in = (mx >= bounds[b * 3 + 0]) & (mx <= bounds[24 + b * 3 + 0]) &
                      (my >= bounds[b * 3 + 1]) & (my <= bounds[24 + b * 3 + 1]) &
                      (mz >= bounds[b * 3 + 2]) & (mz <= bounds[24 + b * 3 + 2]);
            e[b] = in ? msr : -BIG_;
        }
        rec[0] = make_float4(mx, my, mz, 0.f);
        rec[1] = make_float4(e[0], e[2], e[4], e[6]);
        rec[2] = make_float4(e[1], e[3], e[5], e[7]);
    } else {
        rec[0] = make_float4(0.f, 0.f, 0.f, 0.f);
        rec[1] = make_float4(-BIG_, -BIG_, -BIG_, -BIG_);
        rec[2] = make_float4(-BIG_, -BIG_, -BIG_, -BIG_);
    }
}

// K3: main loop. NO LDS, NO barriers. Each thread owns 4 slot-pairs (named
// scalars). Splat records are wave-uniform scalar loads (s_load path): 2 x
// dwordx4 per splat. Waves 0,1 read eff at +16 ({e0,e2,e4,e6}); waves 2,3 at
// +32 ({e1,e3,e5,e7}) -- matches slot->batch mapping batch=(4j+w)>>1.
// Results: plain coalesced stores to res[block][slot] (no contended atomics).
__global__ __launch_bounds__(256) void k_main(const char* __restrict__ wsc,
                                              char* __restrict__ ws) {
    int tid = threadIdx.x;
    const float4* sp = (const float4*)(wsc + SLOT_OFF);
    float4 q0 = sp[tid];
    float4 q1 = sp[tid + 256];
    float4 q2 = sp[tid + 512];
    float4 q3 = sp[tid + 768];

    int effoff = 16 + (((__builtin_amdgcn_readfirstlane(tid) >> 7) & 1) << 4);  // 16 | 32
    const char* rec = wsc + PACK_OFF + (size_t)blockIdx.x * PER * 64;

    float mn0 = BIG_, mn1 = BIG_, mn2 = BIG_, mn3 = BIG_;
#pragma unroll 2
    for (int i = 0; i < PER; i++) {
        float4 pos = *(const float4*)(rec);
        float4 ef  = *(const float4*)(rec + effoff);
        rec += 64;
        float dx, dy, dz, d2;
        dx = q0.x - pos.x; dy = q0.y - pos.y; dz = q0.z - pos.z;
        d2 = fmaf(dz, dz, fmaf(dy, dy, dx * dx));
        mn0 = fminf(mn0, fsqrt(d2) - ef.x);
        dx = q1.x - pos.x; dy = q1.y - pos.y; dz = q1.z - pos.z;
        d2 = fmaf(dz, dz, fmaf(dy, dy, dx * dx));
        mn1 = fminf(mn1, fsqrt(d2) - ef.y);
        dx = q2.x - pos.x; dy = q2.y - pos.y; dz = q2.z - pos.z;
        d2 = fmaf(dz, dz, fmaf(dy, dy, dx * dx));
        mn2 = fminf(mn2, fsqrt(d2) - ef.z);
        dx = q3.x - pos.x; dy = q3.y - pos.y; dz = q3.z - pos.z;
        d2 = fmaf(dz, dz, fmaf(dy, dy, dx * dx));
        mn3 = fminf(mn3, fsqrt(d2) - ef.w);
    }

    float* res = (float*)(ws + RES_OFF) + (size_t)blockIdx.x * NSLOT;
    res[tid]       = mn0;
    res[tid + 256] = mn1;
    res[tid + 512] = mn2;
    res[tid + 768] = mn3;
}

// K4: parallel column-min over res. 64 blocks x 256 threads; block j reduces
// rows [j*16, j*16+16) for all 1024 slots (coalesced), one atomicMin per slot.
// Last block decodes keys, masks dummy slots, writes the scalar.
__global__ __launch_bounds__(256) void k_red(const char* __restrict__ wsc,
                                             char* __restrict__ ws,
                                             float* __restrict__ out) {
    __shared__ int   isLast;
    __shared__ float wsum[4];
    int tid = threadIdx.x;
    const float* res  = (const float*)(wsc + RES_OFF);
    unsigned*    keys = (unsigned*)(ws + KEYS_OFF);
    unsigned*    cnt  = (unsigned*)(ws + CNT_OFF);

    const float* row = res + (size_t)blockIdx.x * KCH * NSLOT;
    float mn0 = BIG_, mn1 = BIG_, mn2 = BIG_, mn3 = BIG_;
#pragma unroll
    for (int i = 0; i < KCH; i++) {
        mn0 = fminf(mn0, row[tid]);
        mn1 = fminf(mn1, row[tid + 256]);
        mn2 = fminf(mn2, row[tid + 512]);
        mn3 = fminf(mn3, row[tid + 768]);
        row += NSLOT;
    }
    atomicMin(&keys[tid],       fkey(mn0));
    atomicMin(&keys[tid + 256], fkey(mn1));
    atomicMin(&keys[tid + 512], fkey(mn2));
    atomicMin(&keys[tid + 768], fkey(mn3));

    __threadfence();  // release: make our atomicMin results visible
    if (tid == 0) isLast = (atomicAdd(cnt, 1u) == (unsigned)(NRED - 1));
    __syncthreads();
    if (isLast) {
        __threadfence();  // acquire: see all blocks' results
        float acc = 0.f;
        for (int s = tid; s < NSLOT; s += 256) {
            if ((s & 127) < T_) {
                unsigned k = __hip_atomic_load(&keys[s], __ATOMIC_RELAXED, __HIP_MEMORY_SCOPE_AGENT);
                unsigned u = (k & 0x80000000u) ? (k ^ 0x80000000u) : ~k;
                acc += fmaxf(0.f, -__uint_as_float(u));
            }
        }
#pragma unroll
        for (int off = 32; off; off >>= 1) acc += __shfl_down(acc, off, 64);
        if ((tid & 63) == 0) wsum[tid >> 6] = acc;
        __syncthreads();
        if (tid == 0)
            out[0] = (wsum[0] + wsum[1] + wsum[2] + wsum[3]) * (1.0f / (float)NPAIRS);
    }
}

extern "C" void kernel_launch(void* const* d_in, const int* in_sizes, int n_in,
                              void* d_out, int out_size, void* d_ws, size_t ws_size,
                              hipStream_t stream) {
    const float* outputs = (const float*)d_in[0];   // (B,T,3)
    const float* c2ws    = (const float*)d_in[1];   // (B,4,4)
    const float* ss      = (const float*)d_in[2];   // (B,)
    const float* means   = (const float*)d_in[3];   // (N,3)
    const float* scales  = (const float*)d_in[4];   // (N,3)
    float* out = (float*)d_out;
    char*  ws  = (char*)d_ws;

    hipLaunchKernelGGL(k_prep, dim3(1), dim3(1024), 0, stream, outputs, c2ws, ss, ws);
    hipLaunchKernelGGL(k_pack, dim3(NREC / 256), dim3(256), 0, stream, means, scales, ws);
    hipLaunchKernelGGL(k_main, dim3(NBLK), dim3(256), 0, stream, (const char*)ws, ws);
    hipLaunchKernelGGL(k_red, dim3(NRED), dim3(256), 0, stream, (const char*)ws, ws, out);
}

// Round 9
// 98.702 us; speedup vs baseline: 2.6098x; 1.1102x over previous
//
#include <hip/hip_runtime.h>

// Problem constants (match reference)
constexpr int   B_ = 8;
constexpr int   T_ = 100;
constexpr int   NPAIRS = B_ * T_;      // 800
constexpr int   N_ = 100000;
constexpr float MARGIN_ = 0.1f;
constexpr float THRESHOLD_ = 0.5f;
constexpr float BIG_ = 1000000000.0f;

// Main-kernel geometry
constexpr int PER   = 98;              // splats per block
constexpr int NBLK  = 1024;            // k_main blocks (4/CU, 16 waves/CU)
constexpr int NSLOT = 1024;            // padded pair slots (8 batches x 128)
constexpr int KCH   = 16;              // res-rows per reduction block
constexpr int NRED  = NBLK / KCH;      // 64 reduction blocks

// Workspace layout (bytes)
constexpr size_t RES_OFF    = 0;                                   // float[NBLK][NSLOT] = 4MB
constexpr size_t SLOT_OFF   = RES_OFF + (size_t)NBLK * NSLOT * 4;  // float4[NSLOT]
constexpr size_t BOUNDS_OFF = SLOT_OFF + (size_t)NSLOT * 16;       // float[48]: l[8][3], u[8][3]
constexpr size_t KEYS_OFF   = BOUNDS_OFF + 256;                    // uint[NSLOT] min-keys
constexpr size_t CNT_OFF    = KEYS_OFF + (size_t)NSLOT * 4;        // uint: finished-block counter

// fast hardware sqrt: single v_sqrt_f32
__device__ __forceinline__ float fsqrt(float x) { return __builtin_amdgcn_sqrtf(x); }

// Map float -> uint such that uint order == float order (handles negatives).
__device__ __forceinline__ unsigned fkey(float f) {
    unsigned u = __float_as_uint(f);
    return (u & 0x80000000u) ? ~u : (u | 0x80000000u);
}

// K1: retrajs -> padded slot-pairs, per-b AABB bounds, init keys+cnt. 1 block x 1024.
// Slot g (0..1023): batch = g>>7, r = g&127; r<100 -> pair batch*100+r, else dummy.
__global__ void k_prep(const float* __restrict__ outputs,
                       const float* __restrict__ c2ws,
                       const float* __restrict__ ss,
                       char* ws) {
    __shared__ float re_s[NPAIRS * 3];
    int tid = threadIdx.x;
    float* bounds = (float*)(ws + BOUNDS_OFF);

    ((unsigned*)(ws + KEYS_OFF))[tid] = fkey(BIG_);   // re-init every call (ws re-poisoned)
    if (tid == 0) *(unsigned*)(ws + CNT_OFF) = 0;

    if (tid < NPAIRS) {
        int b = tid / T_;
        float s = ss[b];
        const float* o = outputs + tid * 3;
        float o0 = o[0], o1 = o[1], o2 = o[2];
        const float* c = c2ws + b * 16;
#pragma unroll
        for (int e = 0; e < 3; e++) {
            re_s[tid * 3 + e] =
                (o0 * c[e * 4 + 0] + o1 * c[e * 4 + 1] + o2 * c[e * 4 + 2]) * s + c[e * 4 + 3];
        }
    }
    __syncthreads();

    if (tid < 24) {
        int b = tid / 3, e = tid - b * 3;
        float mx = -3.4e38f, mn = 3.4e38f;
        for (int t = 0; t < T_; t++) {
            float v = re_s[(b * T_ + t) * 3 + e];
            mx = fmaxf(mx, v);
            mn = fminf(mn, v);
        }
        float thres = THRESHOLD_ * ss[0];  // reference uses scene_scales[0] for all b
        bounds[b * 3 + e]      = mn - thres;  // lvals
        bounds[24 + b * 3 + e] = mx + thres;  // uvals
    }

    // padded slot-pairs
    int bb = tid >> 7, r = tid & 127;
    float4 q = make_float4(0.f, 0.f, 0.f, 0.f);
    if (r < T_) {
        int p = bb * T_ + r;
        q = make_float4(re_s[p * 3 + 0], re_s[p * 3 + 1], re_s[p * 3 + 2], 1.f);
    }
    ((float4*)(ws + SLOT_OFF))[tid] = q;
}

// K2 (fused pack+main): staging phase builds this block's 98 splat records in
// LDS ([pos][e0,e2,e4,e6][e1,e3,e5,e7], 48B each); inner loop reads them as
// WAVE-UNIFORM ds_read_b128 broadcasts (no bank conflicts, no lane-varying
// addrs — the R6 failure mode). Each thread owns 4 slot-pairs as named scalars.
// Waves 0,1 (tid<128) use eff vector 1 (even batches); waves 2,3 use vector 2
// (odd batches) — matches slot->batch = (j*256+tid)>>7 = 2j + (tid>>7).
// Results: plain coalesced stores to res[block][slot].
__global__ __launch_bounds__(256) void k_main(const float* __restrict__ means,
                                              const float* __restrict__ scales,
                                              const char* __restrict__ wsc,
                                              char* __restrict__ ws) {
    __shared__ float4 rec_s[PER * 3];
    int tid = threadIdx.x;
    const float4* sp     = (const float4*)(wsc + SLOT_OFF);
    const float*  bounds = (const float*)(wsc + BOUNDS_OFF);

    float4 q0 = sp[tid];
    float4 q1 = sp[tid + 256];
    float4 q2 = sp[tid + 512];
    float4 q3 = sp[tid + 768];

    // staging: threads 0..97 build records (grid is padded: 1024*98 > N)
    if (tid < PER) {
        int n = blockIdx.x * PER + tid;
        float mx = 0.f, my = 0.f, mz = 0.f;
        float e0, e1, e2, e3, e4, e5, e6, e7;
        if (n < N_) {
            mx = means[(size_t)n * 3 + 0];
            my = means[(size_t)n * 3 + 1];
            mz = means[(size_t)n * 3 + 2];
            float msr = fmaxf(fmaxf(scales[(size_t)n * 3 + 0], scales[(size_t)n * 3 + 1]),
                              scales[(size_t)n * 3 + 2]) + MARGIN_;
            float e[8];
#pragma unroll
            for (int b = 0; b < 8; b++) {
                bool in = (mx >= bounds[b * 3 + 0]) & (mx <= bounds[24 + b * 3 + 0]) &
                          (my >= bounds[b * 3 + 1]) & (my <= bounds[24 + b * 3 + 1]) &
                          (mz >= bounds[b * 3 + 2]) & (mz <= bounds[24 + b * 3 + 2]);
                e[b] = in ? msr : -BIG_;
            }
            e0 = e[0]; e1 = e[1]; e2 = e[2]; e3 = e[3];
            e4 = e[4]; e5 = e[5]; e6 = e[6]; e7 = e[7];
        } else {
            e0 = e1 = e2 = e3 = e4 = e5 = e6 = e7 = -BIG_;
        }
        rec_s[tid * 3 + 0] = make_float4(mx, my, mz, 0.f);
        rec_s[tid * 3 + 1] = make_float4(e0, e2, e4, e6);
        rec_s[tid * 3 + 2] = make_float4(e1, e3, e5, e7);
    }
    __syncthreads();

    // wave-uniform eff selector: 1 for waves 0,1 (even batches), 2 for waves 2,3
    int effidx = 1 + ((__builtin_amdgcn_readfirstlane(tid) >> 7) & 1);

    float mn0 = BIG_, mn1 = BIG_, mn2 = BIG_, mn3 = BIG_;
#pragma unroll 2
    for (int i = 0; i < PER; i++) {
        float4 pos = rec_s[i * 3];
        float4 ef  = rec_s[i * 3 + effidx];
        float dx, dy, dz, d2;
        dx = q0.x - pos.x; dy = q0.y - pos.y; dz = q0.z - pos.z;
        d2 = fmaf(dz, dz, fmaf(dy, dy, dx * dx));
        mn0 = fminf(mn0, fsqrt(d2) - ef.x);
        dx = q1.x - pos.x; dy = q1.y - pos.y; dz = q1.z - pos.z;
        d2 = fmaf(dz, dz, fmaf(dy, dy, dx * dx));
        mn1 = fminf(mn1, fsqrt(d2) - ef.y);
        dx = q2.x - pos.x; dy = q2.y - pos.y; dz = q2.z - pos.z;
        d2 = fmaf(dz, dz, fmaf(dy, dy, dx * dx));
        mn2 = fminf(mn2, fsqrt(d2) - ef.z);
        dx = q3.x - pos.x; dy = q3.y - pos.y; dz = q3.z - pos.z;
        d2 = fmaf(dz, dz, fmaf(dy, dy, dx * dx));
        mn3 = fminf(mn3, fsqrt(d2) - ef.w);
    }

    float* res = (float*)(ws + RES_OFF) + (size_t)blockIdx.x * NSLOT;
    res[tid]       = mn0;
    res[tid + 256] = mn1;
    res[tid + 512] = mn2;
    res[tid + 768] = mn3;
}

// K3: parallel column-min over res. 64 blocks x 256 threads; block j reduces
// rows [j*16, j*16+16) for all 1024 slots (coalesced), one atomicMin per slot.
// Last block decodes keys, masks dummy slots, writes the scalar.
__global__ __launch_bounds__(256) void k_red(const char* __restrict__ wsc,
                                             char* __restrict__ ws,
                                             float* __restrict__ out) {
    __shared__ int   isLast;
    __shared__ float wsum[4];
    int tid = threadIdx.x;
    const float* res  = (const float*)(wsc + RES_OFF);
    unsigned*    keys = (unsigned*)(ws + KEYS_OFF);
    unsigned*    cnt  = (unsigned*)(ws + CNT_OFF);

    const float* row = res + (size_t)blockIdx.x * KCH * NSLOT;
    float mn0 = BIG_, mn1 = BIG_, mn2 = BIG_, mn3 = BIG_;
#pragma unroll
    for (int i = 0; i < KCH; i++) {
        mn0 = fminf(mn0, row[tid]);
        mn1 = fminf(mn1, row[tid + 256]);
        mn2 = fminf(mn2, row[tid + 512]);
        mn3 = fminf(mn3, row[tid + 768]);
        row += NSLOT;
    }
    atomicMin(&keys[tid],       fkey(mn0));
    atomicMin(&keys[tid + 256], fkey(mn1));
    atomicMin(&keys[tid + 512], fkey(mn2));
    atomicMin(&keys[tid + 768], fkey(mn3));

    __threadfence();  // release: make our atomicMin results visible
    if (tid == 0) isLast = (atomicAdd(cnt, 1u) == (unsigned)(NRED - 1));
    __syncthreads();
    if (isLast) {
        __threadfence();  // acquire: see all blocks' results
        float acc = 0.f;
        for (int s = tid; s < NSLOT; s += 256) {
            if ((s & 127) < T_) {
                unsigned k = __hip_atomic_load(&keys[s], __ATOMIC_RELAXED, __HIP_MEMORY_SCOPE_AGENT);
                unsigned u = (k & 0x80000000u) ? (k ^ 0x80000000u) : ~k;
                acc += fmaxf(0.f, -__uint_as_float(u));
            }
        }
#pragma unroll
        for (int off = 32; off; off >>= 1) acc += __shfl_down(acc, off, 64);
        if ((tid & 63) == 0) wsum[tid >> 6] = acc;
        __syncthreads();
        if (tid == 0)
            out[0] = (wsum[0] + wsum[1] + wsum[2] + wsum[3]) * (1.0f / (float)NPAIRS);
    }
}

extern "C" void kernel_launch(void* const* d_in, const int* in_sizes, int n_in,
                              void* d_out, int out_size, void* d_ws, size_t ws_size,
                              hipStream_t stream) {
    const float* outputs = (const float*)d_in[0];   // (B,T,3)
    const float* c2ws    = (const float*)d_in[1];   // (B,4,4)
    const float* ss      = (const float*)d_in[2];   // (B,)
    const float* means   = (const float*)d_in[3];   // (N,3)
    const float* scales  = (const float*)d_in[4];   // (N,3)
    float* out = (float*)d_out;
    char*  ws  = (char*)d_ws;

    hipLaunchKernelGGL(k_prep, dim3(1), dim3(1024), 0, stream, outputs, c2ws, ss, ws);
    hipLaunchKernelGGL(k_main, dim3(NBLK), dim3(256), 0, stream,
                       means, scales, (const char*)ws, ws);
    hipLaunchKernelGGL(k_red, dim3(NRED), dim3(256), 0, stream, (const char*)ws, ws, out);
}

// Round 10
// 96.776 us; speedup vs baseline: 2.6618x; 1.0199x over previous
//
#include <hip/hip_runtime.h>

// Problem constants (match reference)
constexpr int   B_ = 8;
constexpr int   T_ = 100;
constexpr int   NPAIRS = B_ * T_;      // 800
constexpr int   N_ = 100000;
constexpr float MARGIN_ = 0.1f;
constexpr float THRESHOLD_ = 0.5f;
constexpr float BIG_ = 1000000000.0f;

// Main-kernel geometry
constexpr int PER   = 98;              // splats per block
constexpr int NBLK  = 1024;            // k_main blocks (4/CU, 16 waves/CU)
constexpr int NSLOT = 1024;            // padded pair slots (8 batches x 128)
constexpr int KCH   = 16;              // res-rows per reduction block
constexpr int NRED  = NBLK / KCH;      // 64 reduction blocks

// Workspace layout (bytes)
constexpr size_t RES_OFF  = 0;                                   // float[NBLK][NSLOT] = 4MB
constexpr size_t KEYS_OFF = RES_OFF + (size_t)NBLK * NSLOT * 4;  // uint[NSLOT] min-keys
constexpr size_t CNT_OFF  = KEYS_OFF + (size_t)NSLOT * 4;        // uint: finished-block counter

// fast hardware sqrt: single v_sqrt_f32
__device__ __forceinline__ float fsqrt(float x) { return __builtin_amdgcn_sqrtf(x); }

// Map float -> uint such that uint order == float order (handles negatives).
__device__ __forceinline__ unsigned fkey(float f) {
    unsigned u = __float_as_uint(f);
    return (u & 0x80000000u) ? ~u : (u | 0x80000000u);
}

// K1 (fused prep+pack+main): every block redundantly computes the 800 retrajs
// and 8 AABB boxes in LDS (~0.3 us of math -- cheaper than a k_prep dispatch +
// gap), builds its 98 splat records in LDS, then runs the interaction loop with
// WAVE-UNIFORM ds_read_b128 broadcasts. Each thread owns 4 slot-pairs as named
// scalars. Slot g: batch=g>>7, r=g&127 (r<100 -> real pair, else dummy).
// Waves 0,1 use eff vector 1 (even batches); waves 2,3 vector 2 (odd) --
// matches slot->batch = (j*256+tid)>>7 = 2j + (tid>>7).
// Block 0 also inits keys/cnt for k_red (visible via stream ordering).
// Results: plain coalesced stores to res[block][slot] (no contended atomics).
__global__ __launch_bounds__(256) void k_main(const float* __restrict__ outputs,
                                              const float* __restrict__ c2ws,
                                              const float* __restrict__ ss,
                                              const float* __restrict__ means,
                                              const float* __restrict__ scales,
                                              char* __restrict__ ws) {
    __shared__ float  re_s[NPAIRS * 3];
    __shared__ float  bounds_s[48];
    __shared__ float4 rec_s[PER * 3];
    int tid = threadIdx.x;

    if (blockIdx.x == 0) {  // init for k_red; k_red runs after all k_main blocks
        unsigned* keys = (unsigned*)(ws + KEYS_OFF);
        keys[tid]       = fkey(BIG_);
        keys[tid + 256] = fkey(BIG_);
        keys[tid + 512] = fkey(BIG_);
        keys[tid + 768] = fkey(BIG_);
        if (tid == 0) *(unsigned*)(ws + CNT_OFF) = 0;
    }

    // phase A: retrajs -> LDS (3.125 pairs/thread)
    for (int p = tid; p < NPAIRS; p += 256) {
        int b = p / T_;
        float s = ss[b];
        const float* o = outputs + p * 3;
        float o0 = o[0], o1 = o[1], o2 = o[2];
        const float* c = c2ws + b * 16;
#pragma unroll
        for (int e = 0; e < 3; e++) {
            re_s[p * 3 + e] =
                (o0 * c[e * 4 + 0] + o1 * c[e * 4 + 1] + o2 * c[e * 4 + 2]) * s + c[e * 4 + 3];
        }
    }
    __syncthreads();

    // phase B: per-(batch,axis) AABB bounds (24 lanes, serial over T)
    if (tid < 24) {
        int b = tid / 3, e = tid - b * 3;
        float mx = -3.4e38f, mn = 3.4e38f;
        for (int t = 0; t < T_; t++) {
            float v = re_s[(b * T_ + t) * 3 + e];
            mx = fmaxf(mx, v);
            mn = fminf(mn, v);
        }
        float thres = THRESHOLD_ * ss[0];  // reference uses scene_scales[0] for all b
        bounds_s[b * 3 + e]      = mn - thres;  // lvals
        bounds_s[24 + b * 3 + e] = mx + thres;  // uvals
    }
    __syncthreads();

    // phase C: per-thread slot-pairs from LDS + splat-record staging
    float4 q0, q1, q2, q3;
    {
        float4* qs[4] = {&q0, &q1, &q2, &q3};
#pragma unroll
        for (int j = 0; j < 4; j++) {
            int g = tid + j * 256;
            int bb = g >> 7, r = g & 127;
            float4 q = make_float4(0.f, 0.f, 0.f, 0.f);
            if (r < T_) {
                int p = bb * T_ + r;
                q = make_float4(re_s[p * 3 + 0], re_s[p * 3 + 1], re_s[p * 3 + 2], 0.f);
            }
            *qs[j] = q;
        }
    }
    if (tid < PER) {
        int n = blockIdx.x * PER + tid;  // grid is padded: 1024*98 > N
        float mx = 0.f, my = 0.f, mz = 0.f;
        float e0, e1, e2, e3, e4, e5, e6, e7;
        if (n < N_) {
            mx = means[(size_t)n * 3 + 0];
            my = means[(size_t)n * 3 + 1];
            mz = means[(size_t)n * 3 + 2];
            float msr = fmaxf(fmaxf(scales[(size_t)n * 3 + 0], scales[(size_t)n * 3 + 1]),
                              scales[(size_t)n * 3 + 2]) + MARGIN_;
            float e[8];
#pragma unroll
            for (int b = 0; b < 8; b++) {
                bool in = (mx >= bounds_s[b * 3 + 0]) & (mx <= bounds_s[24 + b * 3 + 0]) &
                          (my >= bounds_s[b * 3 + 1]) & (my <= bounds_s[24 + b * 3 + 1]) &
                          (mz >= bounds_s[b * 3 + 2]) & (mz <= bounds_s[24 + b * 3 + 2]);
                e[b] = in ? msr : -BIG_;
            }
            e0 = e[0]; e1 = e[1]; e2 = e[2]; e3 = e[3];
            e4 = e[4]; e5 = e[5]; e6 = e[6]; e7 = e[7];
        } else {
            e0 = e1 = e2 = e3 = e4 = e5 = e6 = e7 = -BIG_;
        }
        rec_s[tid * 3 + 0] = make_float4(mx, my, mz, 0.f);
        rec_s[tid * 3 + 1] = make_float4(e0, e2, e4, e6);
        rec_s[tid * 3 + 2] = make_float4(e1, e3, e5, e7);
    }
    __syncthreads();

    // wave-uniform eff selector: 1 for waves 0,1 (even batches), 2 for waves 2,3
    int effidx = 1 + ((__builtin_amdgcn_readfirstlane(tid) >> 7) & 1);

    float mn0 = BIG_, mn1 = BIG_, mn2 = BIG_, mn3 = BIG_;
#pragma unroll 2
    for (int i = 0; i < PER; i++) {
        float4 pos = rec_s[i * 3];
        float4 ef  = rec_s[i * 3 + effidx];
        float dx, dy, dz, d2;
        dx = q0.x - pos.x; dy = q0.y - pos.y; dz = q0.z - pos.z;
        d2 = fmaf(dz, dz, fmaf(dy, dy, dx * dx));
        mn0 = fminf(mn0, fsqrt(d2) - ef.x);
        dx = q1.x - pos.x; dy = q1.y - pos.y; dz = q1.z - pos.z;
        d2 = fmaf(dz, dz, fmaf(dy, dy, dx * dx));
        mn1 = fminf(mn1, fsqrt(d2) - ef.y);
        dx = q2.x - pos.x; dy = q2.y - pos.y; dz = q2.z - pos.z;
        d2 = fmaf(dz, dz, fmaf(dy, dy, dx * dx));
        mn2 = fminf(mn2, fsqrt(d2) - ef.z);
        dx = q3.x - pos.x; dy = q3.y - pos.y; dz = q3.z - pos.z;
        d2 = fmaf(dz, dz, fmaf(dy, dy, dx * dx));
        mn3 = fminf(mn3, fsqrt(d2) - ef.w);
    }

    float* res = (float*)(ws + RES_OFF) + (size_t)blockIdx.x * NSLOT;
    res[tid]       = mn0;
    res[tid + 256] = mn1;
    res[tid + 512] = mn2;
    res[tid + 768] = mn3;
}

// K2: parallel column-min over res. 64 blocks x 256 threads; block j reduces
// rows [j*16, j*16+16) for all 1024 slots (coalesced), one atomicMin per slot.
// Last block decodes keys, masks dummy slots, writes the scalar.
__global__ __launch_bounds__(256) void k_red(const char* __restrict__ wsc,
                                             char* __restrict__ ws,
                                             float* __restrict__ out) {
    __shared__ int   isLast;
    __shared__ float wsum[4];
    int tid = threadIdx.x;
    const float* res  = (const float*)(wsc + RES_OFF);
    unsigned*    keys = (unsigned*)(ws + KEYS_OFF);
    unsigned*    cnt  = (unsigned*)(ws + CNT_OFF);

    const float* row = res + (size_t)blockIdx.x * KCH * NSLOT;
    float mn0 = BIG_, mn1 = BIG_, mn2 = BIG_, mn3 = BIG_;
#pragma unroll
    for (int i = 0; i < KCH; i++) {
        mn0 = fminf(mn0, row[tid]);
        mn1 = fminf(mn1, row[tid + 256]);
        mn2 = fminf(mn2, row[tid + 512]);
        mn3 = fminf(mn3, row[tid + 768]);
        row += NSLOT;
    }
    atomicMin(&keys[tid],       fkey(mn0));
    atomicMin(&keys[tid + 256], fkey(mn1));
    atomicMin(&keys[tid + 512], fkey(mn2));
    atomicMin(&keys[tid + 768], fkey(mn3));

    __threadfence();  // release: make our atomicMin results visible
    if (tid == 0) isLast = (atomicAdd(cnt, 1u) == (unsigned)(NRED - 1));
    __syncthreads();
    if (isLast) {
        __threadfence();  // acquire: see all blocks' results
        float acc = 0.f;
        for (int s = tid; s < NSLOT; s += 256) {
            if ((s & 127) < T_) {
                unsigned k = __hip_atomic_load(&keys[s], __ATOMIC_RELAXED, __HIP_MEMORY_SCOPE_AGENT);
                unsigned u = (k & 0x80000000u) ? (k ^ 0x80000000u) : ~k;
                acc += fmaxf(0.f, -__uint_as_float(u));
            }
        }
#pragma unroll
        for (int off = 32; off; off >>= 1) acc += __shfl_down(acc, off, 64);
        if ((tid & 63) == 0) wsum[tid >> 6] = acc;
        __syncthreads();
        if (tid == 0)
            out[0] = (wsum[0] + wsum[1] + wsum[2] + wsum[3]) * (1.0f / (float)NPAIRS);
    }
}

extern "C" void kernel_launch(void* const* d_in, const int* in_sizes, int n_in,
                              void* d_out, int out_size, void* d_ws, size_t ws_size,
                              hipStream_t stream) {
    const float* outputs = (const float*)d_in[0];   // (B,T,3)
    const float* c2ws    = (const float*)d_in[1];   // (B,4,4)
    const float* ss      = (const float*)d_in[2];   // (B,)
    const float* means   = (const float*)d_in[3];   // (N,3)
    const float* scales  = (const float*)d_in[4];   // (N,3)
    float* out = (float*)d_out;
    char*  ws  = (char*)d_ws;

    hipLaunchKernelGGL(k_main, dim3(NBLK), dim3(256), 0, stream,
                       outputs, c2ws, ss, means, scales, ws);
    hipLaunchKernelGGL(k_red, dim3(NRED), dim3(256), 0, stream, (const char*)ws, ws, out);
}